// Round 6
// baseline (5541.301 us; speedup 1.0000x reference)
//
#include <hip/hip_runtime.h>
#include <hip/hip_bf16.h>
#include <cstddef>

// LSTM B=64,S=512,D=H=1024. Round 8 structure:
//  prep: zero tagged-h slab + x->bf16 ; transpose W,U -> [4096][1024] bf16
//  gemm_xw: xW = x@W precomputed (fp32 if ws allows), 128-row m-tile + XCD swizzle.
//  lstm_rec: 256 WGs x 512 thr (8 waves, 1 WG/CU, full residency by capacity).
//   8 batch-blocks of 8 batches; 32 WGs/block each owning 32 h-cols
//   (2 col-slices x 4 gates across the 8 waves). U-slice in registers.
//   h exchange: R2's PROVEN protocol -- gen-tagged dwords ((h16<<16)|gen),
//   sc1 stores (write-through to coherent point), relaxed-agent 8B polls
//   (detection == data load). NO sc0/XCD-local path (R5 showed sc0 polls
//   serve stale data on gfx950 -> abandoned).
//  Win vs R2 grid: WG covers 2x columns => 32 consumer WGs/block instead of 64
//   => coherent-point poll traffic halves (16MB -> 8MB per step).
//  Watchdog (1<<16) on polls: pathological stall fails visibly, no container wedge.

typedef __attribute__((ext_vector_type(8))) short short8;
typedef __attribute__((ext_vector_type(4))) float f32x4;

static constexpr int Bc = 64, Sc = 512, Dc = 1024, Hc = 1024, G4c = 4096;

__device__ __forceinline__ unsigned short f2bf(float f) {
    unsigned int u = __float_as_uint(f);
    u = u + 0x7FFFu + ((u >> 16) & 1u);   // RNE
    return (unsigned short)(u >> 16);
}
__device__ __forceinline__ short f2bfs(float f) { return (short)f2bf(f); }
__device__ __forceinline__ float bf2f(unsigned short u) { return __uint_as_float(((unsigned int)u) << 16); }
__device__ __forceinline__ float sigmoidf_(float x) { return 1.0f / (1.0f + __expf(-x)); }
__device__ __forceinline__ float tanhf_(float x) { return 1.0f - 2.0f / (__expf(2.0f * x) + 1.0f); }

// ---------------- prep: zero h slab + x fp32 -> bf16 ----------------
__global__ void __launch_bounds__(256) prep_misc(const float* __restrict__ x,
                                                 unsigned short* __restrict__ x16,
                                                 unsigned int* __restrict__ hbufs,
                                                 int nz, int n4, int use_x16) {
    const int stride = gridDim.x * 256;
    const int j0 = blockIdx.x * 256 + threadIdx.x;
    for (int k = j0; k < nz; k += stride) hbufs[k] = 0u;   // tags=0 (gen starts at 1)
    if (!use_x16) return;
    for (int i = j0; i < n4; i += stride) {
        const float4 v = ((const float4*)x)[i];
        ushort4 o;
        o.x = f2bf(v.x); o.y = f2bf(v.y); o.z = f2bf(v.z); o.w = f2bf(v.w);
        ((ushort4*)x16)[i] = o;
    }
}

// ---------------- transpose [1024][4096] fp32 -> [4096][1024] bf16 ----------------
__global__ void __launch_bounds__(256) transpose_bf16(const float* __restrict__ src,
                                                      unsigned short* __restrict__ dst) {
    __shared__ unsigned short T[64][72];
    const int kt = blockIdx.x >> 6;   // 0..15
    const int gt = blockIdx.x & 63;   // 0..63
    const int tr = threadIdx.x >> 6;  // 0..3
    const int tc = threadIdx.x & 63;  // 0..63
#pragma unroll
    for (int i = 0; i < 16; ++i) {
        const int r = i * 4 + tr;
        T[tc][r] = f2bf(src[(size_t)(kt * 64 + r) * G4c + gt * 64 + tc]);
    }
    __syncthreads();
#pragma unroll
    for (int i = 0; i < 16; ++i) {
        const int g = i * 4 + tr;
        dst[(size_t)(gt * 64 + g) * 1024 + kt * 64 + tc] = T[g][tc];
    }
}

// ---------------- xW GEMM: M=32768 (b,s), N=4096, K=1024; out layout [s][b][4096] ----------------
__global__ void __launch_bounds__(256) gemm_xw(const unsigned short* __restrict__ x16,
                                               const unsigned short* __restrict__ w16t,
                                               void* __restrict__ xw, int mode) {
    const int wg = blockIdx.x;                  // 16384 WGs
    const int swz = (wg & 7) * 2048 + (wg >> 3);
    const int nt = swz >> 8;                    // 0..63
    const int mt = swz & 255;                   // 0..255 (128 rows each)
    const int w = threadIdx.x >> 6;
    const int lane = threadIdx.x & 63;
    const int q = lane >> 4, l16 = lane & 15;

    const unsigned short* abase = x16 + (size_t)(mt * 128 + w * 16 + l16) * 1024 + q * 8;
    const unsigned short* bbase = w16t + (size_t)(nt * 64 + l16) * 1024 + q * 8;

    f32x4 acc0[4] = {{0,0,0,0},{0,0,0,0},{0,0,0,0},{0,0,0,0}};
    f32x4 acc1[4] = {{0,0,0,0},{0,0,0,0},{0,0,0,0},{0,0,0,0}};
#pragma unroll 4
    for (int kk = 0; kk < 32; ++kk) {
        short8 a0 = *(const short8*)(abase + kk * 32);
        short8 a1 = *(const short8*)(abase + 64 * 1024 + kk * 32);
#pragma unroll
        for (int j = 0; j < 4; ++j) {
            short8 b = *(const short8*)(bbase + (size_t)j * 16 * 1024 + kk * 32);
            acc0[j] = __builtin_amdgcn_mfma_f32_16x16x32_bf16(a0, b, acc0[j], 0, 0, 0);
            acc1[j] = __builtin_amdgcn_mfma_f32_16x16x32_bf16(a1, b, acc1[j], 0, 0, 0);
        }
    }
    const int m0 = mt * 128 + w * 16 + q * 4;
#pragma unroll
    for (int half = 0; half < 2; ++half) {
#pragma unroll
        for (int j = 0; j < 4; ++j)
#pragma unroll
            for (int r = 0; r < 4; ++r) {
                const int m = m0 + half * 64 + r;
                const int b = m >> 9, s = m & 511;
                const size_t o = ((size_t)s * 64 + b) * G4c + nt * 64 + j * 16 + l16;
                const float v = half ? acc1[j][r] : acc0[j][r];
                if (mode == 2) ((float*)xw)[o] = v;
                else ((unsigned short*)xw)[o] = f2bf(v);
            }
    }
}

// ---------------- recurrence (512 threads, barrier-free tagged exchange) ----------------
__global__ void __launch_bounds__(512, 2) lstm_rec(
    const unsigned short* __restrict__ x16, const float* __restrict__ x,
    const unsigned short* __restrict__ w16t, const unsigned short* __restrict__ u16t,
    const float* __restrict__ bias, const void* __restrict__ xw,
    unsigned int* __restrict__ hbufs,
    float* __restrict__ out, int xw_mode, int use_x16) {
    extern __shared__ char smem[];
    short8* hsF = (short8*)smem;                                    // 32 KB: h A-frags [kk][lane] (rows 8-15 zero)
    float (*gbuf)[4][16][17] = (float (*)[4][16][17])(smem + 32768);  // [2][4][16][17] = 8704 B
    short8* xsF = (short8*)(smem + 41472);                          // 32 KB, mode 0 only

    const int tid = threadIdx.x;
    const int bid = blockIdx.x;
    const int blk = bid & 7;              // batch block 0..7 (8 batches each)
    const int cs = bid >> 3;              // col slice 0..31 (32 cols each)
    const int col0 = cs * 32;
    const int wv = tid >> 6;              // wave 0..7
    const int lane = tid & 63;
    const int q = lane >> 4, l16 = lane & 15;
    const int g = wv & 3;                 // gate
    const int cs2 = wv >> 2;              // col half (0/1) within WG
    const int bb = tid >> 5, cc = tid & 31;   // elementwise (batch, col-in-WG)
    const int gcol = col0 + cc;
    const bool actE = (bb < 8);
    const int b3 = tid & 7, u6 = tid >> 3;    // poll decomposition (all 512 threads)

    // bias registers
    const float bi = bias[gcol], bfv = bias[1024 + gcol], bg = bias[2048 + gcol], bo = bias[3072 + gcol];

    // U slice -> registers: 32 x short8 = 128 VGPRs (wave = gate g, cols col0+cs2*16..+15)
    short8 uf[32];
    {
        const unsigned short* ub = u16t + ((size_t)(g * 1024 + col0 + cs2 * 16 + l16)) * 1024 + q * 8;
#pragma unroll
        for (int kk = 0; kk < 32; ++kk) uf[kk] = *(const short8*)(ub + kk * 32);
    }
    // zero h frags (h_{-1}=0; rows 8-15 stay zero forever)
    {
        const short8 z = {0, 0, 0, 0, 0, 0, 0, 0};
#pragma unroll
        for (int i = 0; i < 4; ++i) hsF[i * 512 + tid] = z;
        if (xw_mode == 0) {
#pragma unroll
            for (int i = 0; i < 4; ++i) xsF[i * 512 + tid] = z;
        }
    }
    // mode 0: stage x frags for t=0
    if (xw_mode == 0) {
#pragma unroll
        for (int i = 0; i < 4; ++i) {
            const int f = i * 512 + tid;
            const int kk = f >> 6, qq = (f >> 4) & 3, b2 = f & 15;
            if (b2 < 8) {
                if (use_x16) {
                    const unsigned short* xs = x16 + ((size_t)(blk * 8 + b2) * Sc + 0) * Dc + kk * 32 + qq * 8;
                    xsF[f] = *(const short8*)xs;
                } else {
                    const float* xs = x + ((size_t)(blk * 8 + b2) * Sc + 0) * Dc + kk * 32 + qq * 8;
                    float4 v0 = *(const float4*)xs, v1 = *(const float4*)(xs + 4);
                    short8 s;
                    s[0] = f2bfs(v0.x); s[1] = f2bfs(v0.y); s[2] = f2bfs(v0.z); s[3] = f2bfs(v0.w);
                    s[4] = f2bfs(v1.x); s[5] = f2bfs(v1.y); s[6] = f2bfs(v1.z); s[7] = f2bfs(v1.w);
                    xsF[f] = s;
                }
            }
        }
    }
    // prefetch xW(t=0)
    float pxi = 0.f, pxf = 0.f, pxg = 0.f, pxo = 0.f;
    if (actE) {
        if (xw_mode == 1) {
            const unsigned short* p = (const unsigned short*)xw + ((size_t)0 * 64 + blk * 8 + bb) * G4c + gcol;
            pxi = bf2f(p[0]); pxf = bf2f(p[1024]); pxg = bf2f(p[2048]); pxo = bf2f(p[3072]);
        } else if (xw_mode == 2) {
            const float* p = (const float*)xw + ((size_t)0 * 64 + blk * 8 + bb) * G4c + gcol;
            pxi = p[0]; pxf = p[1024]; pxg = p[2048]; pxo = p[3072];
        }
    }

    float c = 0.f;
    for (int t = 0; t < Sc; ++t) {
        __syncthreads();   // staging (or init) visible
        f32x4 a0 = {0, 0, 0, 0}, a1 = {0, 0, 0, 0}, a2 = {0, 0, 0, 0}, a3 = {0, 0, 0, 0};
#pragma unroll
        for (int kk = 0; kk < 32; kk += 4) {
            a0 = __builtin_amdgcn_mfma_f32_16x16x32_bf16(hsF[kk * 64 + lane], uf[kk], a0, 0, 0, 0);
            a1 = __builtin_amdgcn_mfma_f32_16x16x32_bf16(hsF[(kk + 1) * 64 + lane], uf[kk + 1], a1, 0, 0, 0);
            a2 = __builtin_amdgcn_mfma_f32_16x16x32_bf16(hsF[(kk + 2) * 64 + lane], uf[kk + 2], a2, 0, 0, 0);
            a3 = __builtin_amdgcn_mfma_f32_16x16x32_bf16(hsF[(kk + 3) * 64 + lane], uf[kk + 3], a3, 0, 0, 0);
        }
        if (xw_mode == 0) {
            const unsigned short* wb = w16t + ((size_t)(g * 1024 + col0 + cs2 * 16 + l16)) * 1024 + q * 8;
#pragma unroll
            for (int kk = 0; kk < 32; kk += 4) {
                short8 w0 = *(const short8*)(wb + kk * 32);
                a0 = __builtin_amdgcn_mfma_f32_16x16x32_bf16(xsF[kk * 64 + lane], w0, a0, 0, 0, 0);
                short8 w1 = *(const short8*)(wb + (kk + 1) * 32);
                a1 = __builtin_amdgcn_mfma_f32_16x16x32_bf16(xsF[(kk + 1) * 64 + lane], w1, a1, 0, 0, 0);
                short8 w2 = *(const short8*)(wb + (kk + 2) * 32);
                a2 = __builtin_amdgcn_mfma_f32_16x16x32_bf16(xsF[(kk + 2) * 64 + lane], w2, a2, 0, 0, 0);
                short8 w3 = *(const short8*)(wb + (kk + 3) * 32);
                a3 = __builtin_amdgcn_mfma_f32_16x16x32_bf16(xsF[(kk + 3) * 64 + lane], w3, a3, 0, 0, 0);
            }
        }
#pragma unroll
        for (int r = 0; r < 4; ++r) gbuf[cs2][g][q * 4 + r][l16] = (a0[r] + a1[r]) + (a2[r] + a3[r]);
        __syncthreads();
        if (actE) {
            const int ch = cc >> 4, c16 = cc & 15;
            float gi = gbuf[ch][0][bb][c16] + pxi + bi;
            float gf = gbuf[ch][1][bb][c16] + pxf + bfv;
            float gg = gbuf[ch][2][bb][c16] + pxg + bg;
            float go = gbuf[ch][3][bb][c16] + pxo + bo;
            gi = sigmoidf_(gi); gf = sigmoidf_(gf); gg = tanhf_(gg); go = sigmoidf_(go);
            c = gf * c + gi * gg;
            const float h = go * tanhf_(c);
            // gen-tagged h store: single dword (tag co-atomic with data), sc1 -> coherent point
            const unsigned int tagv = ((unsigned int)f2bf(h) << 16) | (unsigned int)(t + 1);
            unsigned int* hp = hbufs + (((size_t)(t & 1)) << 16) + (size_t)(blk * 8 + bb) * 1024 + gcol;
            asm volatile("global_store_dword %0, %1, off sc1" :: "v"(hp), "v"(tagv) : "memory");
            out[((size_t)(blk * 8 + bb) * Sc + t) * Hc + gcol] = h;
            if (t == Sc - 1) {
                out[(size_t)Bc * Sc * Hc + (size_t)(blk * 8 + bb) * Hc + gcol] = h;
                out[(size_t)Bc * Sc * Hc + (size_t)Bc * Hc + (size_t)(blk * 8 + bb) * Hc + gcol] = c;
            }
        }
        if (t < Sc - 1) {
            if (actE) {
                if (xw_mode == 1) {
                    const unsigned short* p = (const unsigned short*)xw + ((size_t)(t + 1) * 64 + blk * 8 + bb) * G4c + gcol;
                    pxi = bf2f(p[0]); pxf = bf2f(p[1024]); pxg = bf2f(p[2048]); pxo = bf2f(p[3072]);
                } else if (xw_mode == 2) {
                    const float* p = (const float*)xw + ((size_t)(t + 1) * 64 + blk * 8 + bb) * G4c + gcol;
                    pxi = p[0]; pxf = p[1024]; pxg = p[2048]; pxo = p[3072];
                }
            }
            // poll own h tile (thread -> batch b3, k-range u6*16..+15); tags inline,
            // so the successful poll IS the data load. 8B relaxed-agent loads (sc1).
            const unsigned int gen = (unsigned int)(t + 1);
            const unsigned long long genpat = (unsigned long long)gen | ((unsigned long long)gen << 32);
            const unsigned long long* pd = (const unsigned long long*)hbufs +
                (((((size_t)(t & 1)) << 16) + (size_t)(blk * 8 + b3) * 1024 + u6 * 16) >> 1);
            unsigned long long hv[8];
            int guard = 0;
            for (;;) {
#pragma unroll
                for (int j = 0; j < 8; ++j)
                    hv[j] = __hip_atomic_load(pd + j, __ATOMIC_RELAXED, __HIP_MEMORY_SCOPE_AGENT);
                unsigned long long bad = 0ull;
#pragma unroll
                for (int j = 0; j < 8; ++j) bad |= (hv[j] ^ genpat) & 0x0000FFFF0000FFFFull;
                if (bad == 0ull || ++guard > (1 << 16)) break;
                __builtin_amdgcn_s_sleep(1);
            }
            // extract h16 (high halves) -> 2 bf16 frags -> LDS
            // thread covers frag (kk = u6>>1), q = (u6&1)*2 + half, lane row b3
#pragma unroll
            for (int half = 0; half < 2; ++half) {
                short8 s;
                unsigned int* sp = (unsigned int*)&s;
#pragma unroll
                for (int w = 0; w < 4; ++w) {
                    const unsigned long long v = hv[half * 4 + w];
                    sp[w] = ((unsigned int)(v >> 16) & 0xFFFFu) | ((unsigned int)(v >> 32) & 0xFFFF0000u);
                }
                hsF[(u6 >> 1) * 64 + ((u6 & 1) * 2 + half) * 16 + b3] = s;
            }
            // stage x_{t+1} frags (mode 0)
            if (xw_mode == 0) {
#pragma unroll
                for (int i = 0; i < 4; ++i) {
                    const int f = i * 512 + tid;
                    const int kk = f >> 6, qq = (f >> 4) & 3, b2 = f & 15;
                    if (b2 < 8) {
                        if (use_x16) {
                            const unsigned short* xs = x16 + ((size_t)(blk * 8 + b2) * Sc + (t + 1)) * Dc + kk * 32 + qq * 8;
                            xsF[f] = *(const short8*)xs;
                        } else {
                            const float* xs = x + ((size_t)(blk * 8 + b2) * Sc + (t + 1)) * Dc + kk * 32 + qq * 8;
                            float4 v0 = *(const float4*)xs, v1 = *(const float4*)(xs + 4);
                            short8 s;
                            s[0] = f2bfs(v0.x); s[1] = f2bfs(v0.y); s[2] = f2bfs(v0.z); s[3] = f2bfs(v0.w);
                            s[4] = f2bfs(v1.x); s[5] = f2bfs(v1.y); s[6] = f2bfs(v1.z); s[7] = f2bfs(v1.w);
                            xsF[f] = s;
                        }
                    }
                }
            }
        }
    }
}

extern "C" void kernel_launch(void* const* d_in, const int* in_sizes, int n_in,
                              void* d_out, int out_size, void* d_ws, size_t ws_size,
                              hipStream_t stream) {
    const float* x = (const float*)d_in[0];
    const float* W = (const float*)d_in[1];
    const float* U = (const float*)d_in[2];
    const float* bias = (const float*)d_in[3];
    float* out = (float*)d_out;

    char* wsb = (char*)d_ws;
    // layout: hbufs(512K) | U16T(8M) | W16T(8M) | x16(64M) | xW
    unsigned int* hbufs = (unsigned int*)wsb;
    unsigned short* u16t = (unsigned short*)(wsb + 524288);
    unsigned short* w16t = (unsigned short*)(wsb + 8912896);
    unsigned short* x16 = (unsigned short*)(wsb + 17301504);
    void* xw = (void*)(wsb + 84410368);

    const size_t base = 84410368ull;
    const size_t need1 = base + 268435456ull;   // xW bf16
    const size_t need2 = base + 536870912ull;   // xW fp32

    int xw_mode, use_x16;
    if (ws_size >= need2)      { xw_mode = 2; use_x16 = 1; }
    else if (ws_size >= need1) { xw_mode = 1; use_x16 = 1; }
    else if (ws_size >= base)  { xw_mode = 0; use_x16 = 1; }
    else                       { xw_mode = 0; use_x16 = 0; }

    const int n4 = (Bc * Sc * Dc) / 4;
    const int nz = 524288 / 4;   // hbufs dwords
    hipLaunchKernelGGL(prep_misc, dim3(2048), dim3(256), 0, stream, x, x16, hbufs, nz, n4, use_x16);
    hipLaunchKernelGGL(transpose_bf16, dim3(1024), dim3(256), 0, stream, U, u16t);
    hipLaunchKernelGGL(transpose_bf16, dim3(1024), dim3(256), 0, stream, W, w16t);
    if (xw_mode >= 1)
        hipLaunchKernelGGL(gemm_xw, dim3(16384), dim3(256), 0, stream, x16, w16t, xw, xw_mode);

    // dynamic LDS: hsF(32K)+gbuf(8704) [+xsF(32K) only in mode 0]
    const unsigned int shmem = (xw_mode == 0) ? 74240u : 41472u;
    if (xw_mode == 0)
        hipFuncSetAttribute((const void*)lstm_rec, hipFuncAttributeMaxDynamicSharedMemorySize, 74240);

    // 256 WGs x 512 thr = 1 WG/CU (8 waves @ ~170 VGPR) -> full residency by capacity.
    hipLaunchKernelGGL(lstm_rec, dim3(256), dim3(512), shmem, stream,
                       x16, x, w16t, u16t, bias, xw, hbufs, out, xw_mode, use_x16);
}